// Round 4
// baseline (1328.310 us; speedup 1.0000x reference)
//
#include <hip/hip_runtime.h>

#define NTOK 4096
#define DIM 32
#define NBH 32              // B*H
#define NPAIR2 528          // upper triangle incl. diagonal of 32x32
#define NROWS 560           // + 32 kv1 rows
#define BHF (NROWS * 32 + 64)       // floats per bh: rows + ksum(32) + vsum(32) = 17984
#define SLOT (NBH * BHF)            // 575488 floats per slot (2.30 MB)
#define TILE 64
#define LSTR 36             // padded LDS row stride; col 32 = 1.0 (kv1), col 34 = 0.0 (dummy)
#define RHALF 320           // padded rows per z-half (2*320 = 640 >= 560)

__device__ __forceinline__ int tri_start(int d) { return (d * (65 - d)) >> 1; }

__device__ __forceinline__ int tri_decode_d(int p) {
    int d = (int)((65.0f - sqrtf((float)(4225 - 8 * p))) * 0.5f);
    if (d < 0) d = 0;
    if (d > 31) d = 31;
    while (d < 31 && tri_start(d + 1) <= p) ++d;
    while (d > 0 && tri_start(d) > p) --d;
    return d;
}

// Phase 1: grid (chunk, bh, rhalf). Wave w owns f-slice [8w, 8w+8); lane l owns 5 rows
// {RHALF*z + 64j + l}. Row p<528: s=k_d*k_e; 528<=p<560: s=k_d*1.0 (pad col 32);
// p>=560: s=0 (pad col 34). acc[5][8] in VGPRs; flush to slot (disjoint rows per z).
__global__ __launch_bounds__(256, 5) void phase1_kernel(const float* __restrict__ qkv,
                                                        float* __restrict__ ws, int direct) {
    const int chunk = blockIdx.x;
    const int bh = blockIdx.y;
    const int h = blockIdx.z;
    const int CH = NTOK / gridDim.x;
    const int t = threadIdx.x;
    const int l = t & 63;
    const int f0 = (t >> 6) << 3;
    const float* kptr = qkv + (size_t)(NBH + bh) * (NTOK * DIM);
    const float* vptr = qkv + (size_t)(2 * NBH + bh) * (NTOK * DIM);
    float* base = ws + (direct ? (size_t)0 : (size_t)SLOT * (1 + chunk)) + (size_t)bh * BHF;

    __shared__ __align__(16) float sk[TILE][LSTR];
    __shared__ __align__(16) float sv[TILE][LSTR];

    const float* ap[5];
    const float* bp[5];
#pragma unroll
    for (int j = 0; j < 5; ++j) {
        const int row = RHALF * h + 64 * j + l;
        int ia, ib;
        if (row < NPAIR2) {
            const int d = tri_decode_d(row);
            ia = d; ib = d + (row - tri_start(d));
        } else if (row < NROWS) {
            ia = row - NPAIR2; ib = 32;
        } else {
            ia = 34; ib = 34;
        }
        ap[j] = &sk[0][ia];
        bp[j] = &sk[0][ib];
    }
    const bool sum_wave = (h == 0) && ((t >> 6) == 3);   // wave-uniform
    const float* sump = (t >= 224) ? &sv[0][t - 224] : ((t >= 192) ? &sk[0][t - 192] : &sk[0][0]);

    float acc[5][8];
#pragma unroll
    for (int j = 0; j < 5; ++j)
#pragma unroll
        for (int f = 0; f < 8; ++f) acc[j][f] = 0.f;
    float accs = 0.f;

    // pad columns (staging never writes cols >= 32; first barrier publishes)
    if (t < 64) sk[t][32] = 1.0f;
    else if (t < 128) sk[t - 64][34] = 0.0f;

    const int n0 = chunk * CH;
    for (int nt = 0; nt < CH; nt += TILE) {
        __syncthreads();
        {
            const float4* kg4 = (const float4*)(kptr + (size_t)(n0 + nt) * DIM);
            const float4* vg4 = (const float4*)(vptr + (size_t)(n0 + nt) * DIM);
            const int i0 = t, i1 = t + 256;
            *(float4*)&sk[i0 >> 3][(i0 & 7) << 2] = kg4[i0];
            *(float4*)&sk[i1 >> 3][(i1 & 7) << 2] = kg4[i1];
            *(float4*)&sv[i0 >> 3][(i0 & 7) << 2] = vg4[i0];
            *(float4*)&sv[i1 >> 3][(i1 & 7) << 2] = vg4[i1];
        }
        __syncthreads();
#pragma unroll 8
        for (int nn = 0; nn < TILE; ++nn) {
            const float4 va = *(const float4*)&sv[nn][f0];
            const float4 vb = *(const float4*)&sv[nn][f0 + 4];
            float s[5];
#pragma unroll
            for (int j = 0; j < 5; ++j) s[j] = ap[j][nn * LSTR] * bp[j][nn * LSTR];
#pragma unroll
            for (int j = 0; j < 5; ++j) {
                acc[j][0] += s[j] * va.x; acc[j][1] += s[j] * va.y;
                acc[j][2] += s[j] * va.z; acc[j][3] += s[j] * va.w;
                acc[j][4] += s[j] * vb.x; acc[j][5] += s[j] * vb.y;
                acc[j][6] += s[j] * vb.z; acc[j][7] += s[j] * vb.w;
            }
            if (sum_wave) accs += sump[nn * LSTR];
        }
    }

    // flush rows (each (row, f-slice) owned by exactly one thread; z-halves disjoint)
#pragma unroll
    for (int j = 0; j < 5; ++j) {
        const int row = RHALF * h + 64 * j + l;
        if (row < NROWS) {
            float* dst = base + (size_t)row * 32 + f0;
            float4 v0; v0.x = acc[j][0]; v0.y = acc[j][1]; v0.z = acc[j][2]; v0.w = acc[j][3];
            float4 v1; v1.x = acc[j][4]; v1.y = acc[j][5]; v1.z = acc[j][6]; v1.w = acc[j][7];
            *(float4*)dst = v0;
            *(float4*)(dst + 4) = v1;
        }
    }
    if (sum_wave) base[NROWS * 32 + (t - 192)] = accs;   // ksum (0..31) then vsum (32..63)
}

// Sum partial slots 1..nch into slot 0.
__global__ __launch_bounds__(256) void reduce_kernel(float* __restrict__ ws, int nch) {
    const int i = blockIdx.x * 256 + threadIdx.x;
    if (i >= SLOT / 4) return;
    float4 a = {0.f, 0.f, 0.f, 0.f};
    for (int c = 1; c <= nch; ++c) {
        const float4 p = ((const float4*)(ws + (size_t)SLOT * c))[i];
        a.x += p.x; a.y += p.y; a.z += p.z; a.w += p.w;
    }
    ((float4*)ws)[i] = a;
}

// Phase 2: lane = token, 16 of 32 f per block (blockIdx.z), rows walked consecutively,
// e-loop unrolled x8 so ~8 rows of wave-uniform scalar loads stay in flight.
__global__ __launch_bounds__(256) void phase2_kernel(const float* __restrict__ qkv,
                                                     const float* __restrict__ ws,
                                                     float* __restrict__ out) {
    const int bh = blockIdx.y;
    const int f0 = blockIdx.z << 4;
    const int t = threadIdx.x;
    const int tok0 = blockIdx.x * 256;
    const float* qptr = qkv + (size_t)bh * (NTOK * DIM) + (size_t)tok0 * DIM;
    const float* base = ws + (size_t)bh * BHF;
    const float* ksum = base + NROWS * 32;
    const float* vsum = ksum + 32;

    __shared__ float qT[32][256];
    {
        const float4* q4 = (const float4*)qptr + (size_t)t * 8;
#pragma unroll
        for (int i = 0; i < 8; ++i) {
            const float4 v = q4[i];
            qT[4 * i + 0][t] = v.x; qT[4 * i + 1][t] = v.y;
            qT[4 * i + 2][t] = v.z; qT[4 * i + 3][t] = v.w;
        }
    }
    __syncthreads();

    float y[16];
#pragma unroll
    for (int j = 0; j < 4; ++j) {
        const float4 v = *(const float4*)(vsum + f0 + 4 * j);
        y[4 * j + 0] = v.x; y[4 * j + 1] = v.y; y[4 * j + 2] = v.z; y[4 * j + 3] = v.w;
    }
    float qk = 0.f;

    const float* rowp = base + f0;   // walks the 528 triangle rows, then 32 kv1 rows
#pragma unroll 1
    for (int d = 0; d < 32; ++d) {
        const float qd = qT[d][t];
        qk += qd * ksum[d];
        {   // diagonal row (e == d): s = 0.5 qd^2
            const float s = 0.5f * qd * qd;
            const float4* r = (const float4*)rowp;
#pragma unroll
            for (int j = 0; j < 4; ++j) {
                const float4 w = r[j];
                y[4 * j + 0] += s * w.x; y[4 * j + 1] += s * w.y;
                y[4 * j + 2] += s * w.z; y[4 * j + 3] += s * w.w;
            }
            rowp += 32;
        }
#pragma unroll 8
        for (int e = d + 1; e < 32; ++e) {
            const float s = qd * qT[e][t];
            const float4* r = (const float4*)rowp;
#pragma unroll
            for (int j = 0; j < 4; ++j) {
                const float4 w = r[j];
                y[4 * j + 0] += s * w.x; y[4 * j + 1] += s * w.y;
                y[4 * j + 2] += s * w.z; y[4 * j + 3] += s * w.w;
            }
            rowp += 32;
        }
    }
    // kv1 rows
#pragma unroll 8
    for (int d = 0; d < 32; ++d) {
        const float qd = qT[d][t];
        const float4* r = (const float4*)rowp;
#pragma unroll
        for (int j = 0; j < 4; ++j) {
            const float4 w = r[j];
            y[4 * j + 0] += qd * w.x; y[4 * j + 1] += qd * w.y;
            y[4 * j + 2] += qd * w.z; y[4 * j + 3] += qd * w.w;
        }
        rowp += 32;
    }

    const float inv = 1.0f / (0.5f * qk * qk + qk + 1.0f);
    float4* o4 = (float4*)(out + (size_t)bh * (NTOK * DIM) + (size_t)(tok0 + t) * DIM + f0);
#pragma unroll
    for (int j = 0; j < 4; ++j) {
        float4 v;
        v.x = y[4 * j + 0] * inv; v.y = y[4 * j + 1] * inv;
        v.z = y[4 * j + 2] * inv; v.w = y[4 * j + 3] * inv;
        o4[j] = v;
    }
}

extern "C" void kernel_launch(void* const* d_in, const int* in_sizes, int n_in,
                              void* d_out, int out_size, void* d_ws, size_t ws_size,
                              hipStream_t stream) {
    const float* qkv = (const float*)d_in[0];
    float* out = (float*)d_out;
    float* ws = (float*)d_ws;

    const size_t slot_bytes = (size_t)SLOT * 4;
    const int avail = (int)(ws_size / slot_bytes) - 1;  // partial slots available
    int nch = 32;
    while (nch > 1 && avail < nch) nch >>= 1;

    if (nch >= 2) {
        phase1_kernel<<<dim3(nch, NBH, 2), dim3(256), 0, stream>>>(qkv, ws, 0);
        reduce_kernel<<<dim3(SLOT / 4 / 256), dim3(256), 0, stream>>>(ws, nch);
    } else {
        phase1_kernel<<<dim3(1, NBH, 2), dim3(256), 0, stream>>>(qkv, ws, 1);
    }
    phase2_kernel<<<dim3(NTOK / 256, NBH, 2), dim3(256), 0, stream>>>(qkv, ws, out);
}

// Round 5
// 177.769 us; speedup vs baseline: 7.4721x; 7.4721x over previous
//
#include <hip/hip_runtime.h>

#define NTOK 4096
#define DIM 32
#define NBH 32              // B*H
#define NPAIR2 528          // upper triangle incl. diagonal of 32x32
#define NROWS 560           // + 32 kv1 rows
#define BHF (NROWS * 32 + 64)       // floats per bh: rows + ksum(32) + vsum(32) = 17984
#define SLOT (NBH * BHF)            // 575488 floats per slot (2.30 MB)
#define TILE 64
#define LSTR 36             // padded LDS row stride; col 32 = 1.0 (kv1), col 34 = 0.0 (dummy)
#define P1T 320             // phase1 threads (5 waves); rows: t and t+320

__device__ __forceinline__ int tri_start(int d) { return (d * (65 - d)) >> 1; }

__device__ __forceinline__ int tri_decode_d(int p) {
    int d = (int)((65.0f - sqrtf((float)(4225 - 8 * p))) * 0.5f);
    if (d < 0) d = 0;
    if (d > 31) d = 31;
    while (d < 31 && tri_start(d + 1) <= p) ++d;
    while (d > 0 && tri_start(d) > p) --d;
    return d;
}

__device__ __forceinline__ void row_operands(int row, int& ia, int& ib) {
    if (row < NPAIR2) {
        const int d = tri_decode_d(row);
        ia = d; ib = d + (row - tri_start(d));
    } else if (row < NROWS) {
        ia = row - NPAIR2; ib = 32;      // kv1 row: s = k_d * 1.0 (pad col 32)
    } else {
        ia = 34; ib = 34;                // dummy row: s = 0 * 0 (pad col 34)
    }
}

// Phase 1: grid (chunk, bh), 320 threads. Thread t owns rows {t, t+320}, full f.
// k staged in LDS (per-lane gather); v read via wave-uniform GLOBAL loads -> SGPRs,
// consumed as the scalar operand of v_fmac. Wave 4 lanes also accumulate ksum/vsum.
__global__ __launch_bounds__(P1T) void phase1_kernel(const float* __restrict__ qkv,
                                                     float* __restrict__ ws, int direct) {
    const int chunk = blockIdx.x;
    const int bh = blockIdx.y;
    const int CHt = NTOK / gridDim.x;
    const int t = threadIdx.x;
    const float* kptr = qkv + (size_t)(NBH + bh) * (NTOK * DIM);
    const float* vptr = qkv + (size_t)(2 * NBH + bh) * (NTOK * DIM);
    float* base = ws + (direct ? (size_t)0 : (size_t)SLOT * (1 + chunk)) + (size_t)bh * BHF;

    __shared__ __align__(16) float sk[TILE][LSTR];
    __shared__ __align__(16) float sv[TILE][LSTR];

    int ia0, ib0, ia1, ib1;
    row_operands(t, ia0, ib0);
    row_operands(t + P1T, ia1, ib1);
    const float* a0 = &sk[0][ia0];
    const float* b0 = &sk[0][ib0];
    const float* a1 = &sk[0][ia1];
    const float* b1 = &sk[0][ib1];
    // wave-4 running sums: lanes 256..287 -> ksum col, 288..319 -> vsum col
    const float* sums = (t >= 288) ? &sv[0][t - 288] : ((t >= 256) ? &sk[0][t - 256] : &sk[0][0]);

    float acc0[32], acc1[32];
#pragma unroll
    for (int f = 0; f < 32; ++f) { acc0[f] = 0.f; acc1[f] = 0.f; }
    float accs = 0.f;

    // pad columns (staging only writes cols 0..31; first barrier publishes)
    if (t < 64) sk[t][32] = 1.0f;
    else if (t < 128) sk[t - 64][34] = 0.0f;

    const int n0 = chunk * CHt;
    for (int nt = 0; nt < CHt; nt += TILE) {
        __syncthreads();
        if (t < 256) {   // wave-uniform: wave 4 skips staging
            const float4* kg4 = (const float4*)(kptr + (size_t)(n0 + nt) * DIM);
            const float4* vg4 = (const float4*)(vptr + (size_t)(n0 + nt) * DIM);
            const int i0 = t, i1 = t + 256;
            *(float4*)&sk[i0 >> 3][(i0 & 7) << 2] = kg4[i0];
            *(float4*)&sk[i1 >> 3][(i1 & 7) << 2] = kg4[i1];
            *(float4*)&sv[i0 >> 3][(i0 & 7) << 2] = vg4[i0];
            *(float4*)&sv[i1 >> 3][(i1 & 7) << 2] = vg4[i1];
        }
        __syncthreads();
#pragma unroll 2
        for (int nn = 0; nn < TILE; ++nn) {
            // per-lane k gather from LDS (broadcast-heavy, <=2-way bank alias)
            const float s0 = a0[nn * LSTR] * b0[nn * LSTR];
            const float s1 = a1[nn * LSTR] * b1[nn * LSTR];
            // wave-uniform v row from GLOBAL -> scalar loads -> SGPR operands
            const float* vrow = vptr + (size_t)(n0 + nt + nn) * DIM;
            float4 w[8];
#pragma unroll
            for (int j = 0; j < 8; ++j) w[j] = ((const float4*)vrow)[j];
#pragma unroll
            for (int j = 0; j < 8; ++j) {
                acc0[4 * j + 0] += s0 * w[j].x; acc0[4 * j + 1] += s0 * w[j].y;
                acc0[4 * j + 2] += s0 * w[j].z; acc0[4 * j + 3] += s0 * w[j].w;
                acc1[4 * j + 0] += s1 * w[j].x; acc1[4 * j + 1] += s1 * w[j].y;
                acc1[4 * j + 2] += s1 * w[j].z; acc1[4 * j + 3] += s1 * w[j].w;
            }
            if (t >= 256) accs += sums[nn * LSTR];   // wave-uniform branch
        }
    }

    // flush rows (row0 = t always real; row1 real iff t < 240)
    {
        float* dst = base + (size_t)t * 32;
#pragma unroll
        for (int j = 0; j < 8; ++j) {
            float4 v; v.x = acc0[4 * j]; v.y = acc0[4 * j + 1];
            v.z = acc0[4 * j + 2]; v.w = acc0[4 * j + 3];
            ((float4*)dst)[j] = v;
        }
    }
    if (t < 240) {
        float* dst = base + (size_t)(t + P1T) * 32;
#pragma unroll
        for (int j = 0; j < 8; ++j) {
            float4 v; v.x = acc1[4 * j]; v.y = acc1[4 * j + 1];
            v.z = acc1[4 * j + 2]; v.w = acc1[4 * j + 3];
            ((float4*)dst)[j] = v;
        }
    }
    if (t >= 256) base[NROWS * 32 + (t - 256)] = accs;   // ksum (0..31), vsum (32..63)
}

// Sum partial slots 1..nch into slot 0.
__global__ __launch_bounds__(256) void reduce_kernel(float* __restrict__ ws, int nch) {
    const int i = blockIdx.x * 256 + threadIdx.x;
    if (i >= SLOT / 4) return;
    float4 a = {0.f, 0.f, 0.f, 0.f};
    for (int c = 1; c <= nch; ++c) {
        const float4 p = ((const float4*)(ws + (size_t)SLOT * c))[i];
        a.x += p.x; a.y += p.y; a.z += p.z; a.w += p.w;
    }
    ((float4*)ws)[i] = a;
}

// Phase 2: lane = token, 16 of 32 f per block (blockIdx.z), rows walked consecutively,
// e-loop unrolled x8 so ~8 rows of wave-uniform scalar loads stay in flight.
__global__ __launch_bounds__(256) void phase2_kernel(const float* __restrict__ qkv,
                                                     const float* __restrict__ ws,
                                                     float* __restrict__ out) {
    const int bh = blockIdx.y;
    const int f0 = blockIdx.z << 4;
    const int t = threadIdx.x;
    const int tok0 = blockIdx.x * 256;
    const float* qptr = qkv + (size_t)bh * (NTOK * DIM) + (size_t)tok0 * DIM;
    const float* base = ws + (size_t)bh * BHF;
    const float* ksum = base + NROWS * 32;
    const float* vsum = ksum + 32;

    __shared__ float qT[32][256];
    {
        const float4* q4 = (const float4*)qptr + (size_t)t * 8;
#pragma unroll
        for (int i = 0; i < 8; ++i) {
            const float4 v = q4[i];
            qT[4 * i + 0][t] = v.x; qT[4 * i + 1][t] = v.y;
            qT[4 * i + 2][t] = v.z; qT[4 * i + 3][t] = v.w;
        }
    }
    __syncthreads();

    float y[16];
#pragma unroll
    for (int j = 0; j < 4; ++j) {
        const float4 v = *(const float4*)(vsum + f0 + 4 * j);
        y[4 * j + 0] = v.x; y[4 * j + 1] = v.y; y[4 * j + 2] = v.z; y[4 * j + 3] = v.w;
    }
    float qk = 0.f;

    const float* rowp = base + f0;   // walks the 528 triangle rows, then 32 kv1 rows
#pragma unroll 1
    for (int d = 0; d < 32; ++d) {
        const float qd = qT[d][t];
        qk += qd * ksum[d];
        {   // diagonal row (e == d): s = 0.5 qd^2
            const float s = 0.5f * qd * qd;
            const float4* r = (const float4*)rowp;
#pragma unroll
            for (int j = 0; j < 4; ++j) {
                const float4 w = r[j];
                y[4 * j + 0] += s * w.x; y[4 * j + 1] += s * w.y;
                y[4 * j + 2] += s * w.z; y[4 * j + 3] += s * w.w;
            }
            rowp += 32;
        }
#pragma unroll 8
        for (int e = d + 1; e < 32; ++e) {
            const float s = qd * qT[e][t];
            const float4* r = (const float4*)rowp;
#pragma unroll
            for (int j = 0; j < 4; ++j) {
                const float4 w = r[j];
                y[4 * j + 0] += s * w.x; y[4 * j + 1] += s * w.y;
                y[4 * j + 2] += s * w.z; y[4 * j + 3] += s * w.w;
            }
            rowp += 32;
        }
    }
    // kv1 rows
#pragma unroll 8
    for (int d = 0; d < 32; ++d) {
        const float qd = qT[d][t];
        const float4* r = (const float4*)rowp;
#pragma unroll
        for (int j = 0; j < 4; ++j) {
            const float4 w = r[j];
            y[4 * j + 0] += qd * w.x; y[4 * j + 1] += qd * w.y;
            y[4 * j + 2] += qd * w.z; y[4 * j + 3] += qd * w.w;
        }
        rowp += 32;
    }

    const float inv = 1.0f / (0.5f * qk * qk + qk + 1.0f);
    float4* o4 = (float4*)(out + (size_t)bh * (NTOK * DIM) + (size_t)(tok0 + t) * DIM + f0);
#pragma unroll
    for (int j = 0; j < 4; ++j) {
        float4 v;
        v.x = y[4 * j + 0] * inv; v.y = y[4 * j + 1] * inv;
        v.z = y[4 * j + 2] * inv; v.w = y[4 * j + 3] * inv;
        o4[j] = v;
    }
}

extern "C" void kernel_launch(void* const* d_in, const int* in_sizes, int n_in,
                              void* d_out, int out_size, void* d_ws, size_t ws_size,
                              hipStream_t stream) {
    const float* qkv = (const float*)d_in[0];
    float* out = (float*)d_out;
    float* ws = (float*)d_ws;

    const size_t slot_bytes = (size_t)SLOT * 4;
    const int avail = (int)(ws_size / slot_bytes) - 1;  // partial slots available
    int nch = 32;
    while (nch > 1 && avail < nch) nch >>= 1;

    if (nch >= 2) {
        phase1_kernel<<<dim3(nch, NBH), dim3(P1T), 0, stream>>>(qkv, ws, 0);
        reduce_kernel<<<dim3(SLOT / 4 / 256), dim3(256), 0, stream>>>(ws, nch);
    } else {
        phase1_kernel<<<dim3(1, NBH), dim3(P1T), 0, stream>>>(qkv, ws, 1);
    }
    phase2_kernel<<<dim3(NTOK / 256, NBH, 2), dim3(256), 0, stream>>>(qkv, ws, out);
}